// Round 5
// baseline (354.720 us; speedup 1.0000x reference)
//
#include <hip/hip_runtime.h>

// Local variance over a 5x5 sliding window, reflect padding.
// SEPARABLE, VERTICAL-FIRST with non-draining barriers. Identical to the
// previous round EXCEPT __launch_bounds__(256,4) -> (256,6).
//
// Round-4 diagnosis: OccupancyPercent 43.7% == 14/32 waves/CU. The grid is
// 1536 blocks = 6 blocks/CU, but launch_bounds(,4) capped residency at 4
// blocks/CU -> a 4-block round plus a half-idle 2-block tail, and only 16
// waves/CU to hide the ~400-600 cyc per-row ds_write->barrier->ds_read
// chain (measured per-wave iteration ~1420 cyc = chain/4 waves-per-SIMD).
// VALUBusy 9.8%, BW 2.45 TB/s, conflicts ~5 us total: pure TLP starvation.
// With (,6): all 6 blocks co-resident (VGPR 48 <= 64-reg step, LDS 96 KB of
// 160), no tail round, 24 waves/CU.
//
//   pass 1 (registers): vertical 5-row running sums of x and x^2 per thread
//     for its own 4 columns (1 float4 load per row, perfectly coalesced).
//   pass 2 (LDS): vertical sums staged in a double-buffered LDS row;
//     horizontal 5-window read from LDS. Raw s_barrier preceded by an
//     lgkmcnt(0)-only wait so the depth-2 global prefetch stays in flight
//     across barriers.
//
// Reflect (jnp "reflect"): rows wave-uniform; columns:
//   left  (c0==0):  col -2 -> col 2 (auto via clamped read); col -1 -> col 1 = sv1
//   right (c0==W-4): col W -> col W-2 = sv2; col W+1 -> col W-3 (auto)

constexpr int NT = 256;
constexpr int RH = 32;

typedef float v4f __attribute__((ext_vector_type(4)));

__global__ __launch_bounds__(NT, 6)
void lvar5x5_sep3_kernel(const float* __restrict__ in, float* __restrict__ out,
                         int H, int W) {
    const int tx = threadIdx.x;          // 0..255, covers full row
    const int c0 = tx * 4;               // this thread's 4 columns
    const int r0 = blockIdx.x * RH;      // first output row
    const size_t plane = (size_t)H * W;
    const float* __restrict__ img = in + (size_t)blockIdx.y * plane;
    float* __restrict__ o = out + (size_t)blockIdx.y * plane;

    __shared__ float lsv[2][1024];       // staged vertical sums of x
    __shared__ float lsq[2][1024];       // staged vertical sums of x^2

    const bool cL = (c0 == 0);
    const bool cR = (c0 == W - 4);
    const int a0 = cL ? 0 : c0 - 4;      // clamped left window read (floats)
    const int a2 = cR ? c0 : c0 + 4;     // clamped right window read

    float ring[5][4];                    // raw x ring (x^2 recomputed on retire)
    float sv0 = 0.f, sv1 = 0.f, sv2 = 0.f, sv3 = 0.f;
    float sq0 = 0.f, sq1 = 0.f, sq2 = 0.f, sq3 = 0.f;
    const float inv = 1.0f / 25.0f;

    auto row_ptr = [&](int i) -> const float4* {
        int gy = r0 - 2 + i;
        gy = (gy < 0) ? -gy : ((gy >= H) ? (2 * H - 2 - gy) : gy);
        return reinterpret_cast<const float4*>(img + (size_t)gy * W + c0);
    };

    float4 vc = *row_ptr(0);             // current row
    float4 vn = *row_ptr(1);             // next row (in flight)

#pragma unroll
    for (int i = 0; i < RH + 4; ++i) {
        // depth-2 prefetch: issue row i+2 now; consumed two iterations later
        float4 vf;
        if (i + 2 < RH + 4) vf = *row_ptr(i + 2);

        const int s = i % 5;             // compile-time after unroll
        if (i >= 5) {
            const float o0 = ring[s][0], o1 = ring[s][1],
                        o2 = ring[s][2], o3 = ring[s][3];
            sv0 -= o0; sv1 -= o1; sv2 -= o2; sv3 -= o3;
            sq0 = fmaf(-o0, o0, sq0); sq1 = fmaf(-o1, o1, sq1);
            sq2 = fmaf(-o2, o2, sq2); sq3 = fmaf(-o3, o3, sq3);
        }
        ring[s][0] = vc.x; ring[s][1] = vc.y; ring[s][2] = vc.z; ring[s][3] = vc.w;
        sv0 += vc.x; sv1 += vc.y; sv2 += vc.z; sv3 += vc.w;
        sq0 = fmaf(vc.x, vc.x, sq0); sq1 = fmaf(vc.y, vc.y, sq1);
        sq2 = fmaf(vc.z, vc.z, sq2); sq3 = fmaf(vc.w, vc.w, sq3);

        if (i >= 4) {
            const int sl = i & 1;
            *reinterpret_cast<float4*>(&lsv[sl][c0]) =
                make_float4(sv0, sv1, sv2, sv3);
            *reinterpret_cast<float4*>(&lsq[sl][c0]) =
                make_float4(sq0, sq1, sq2, sq3);

            // non-draining barrier: wait own LDS writes only, keep the
            // global prefetch (vmcnt) in flight across the barrier.
            asm volatile("s_waitcnt lgkmcnt(0)" ::: "memory");
            __builtin_amdgcn_sched_barrier(0);
            __builtin_amdgcn_s_barrier();
            __builtin_amdgcn_sched_barrier(0);

            const float4 u0 = *reinterpret_cast<const float4*>(&lsv[sl][a0]);
            const float4 u2 = *reinterpret_cast<const float4*>(&lsv[sl][a2]);
            const float4 w0 = *reinterpret_cast<const float4*>(&lsq[sl][a0]);
            const float4 w2 = *reinterpret_cast<const float4*>(&lsq[sl][a2]);

            // window cols c0-2 .. c0+5 of the vertical sums
            const float t2 = u0.z;                   // c0-2 (auto at left edge)
            float       t3 = cL ? sv1 : u0.w;        // c0-1 (reflect -1 -> 1)
            float       t8 = cR ? sv2 : u2.x;        // c0+4 (reflect W -> W-2)
            const float t9 = u2.y;                   // c0+5 (auto at right edge)

            const float g2 = w0.z;
            float       g3 = cL ? sq1 : w0.w;
            float       g8 = cR ? sq2 : w2.x;
            const float g9 = w2.y;

            const float h0 = t2 + t3 + sv0 + sv1 + sv2;
            const float h1 = h0 - t2 + sv3;
            const float h2 = h1 - t3 + t8;
            const float h3 = h2 - sv0 + t9;

            const float q0 = g2 + g3 + sq0 + sq1 + sq2;
            const float q1 = q0 - g2 + sq3;
            const float q2 = q1 - g3 + g8;
            const float q3 = q2 - sq0 + g9;

            v4f res;
            float m;
            m = h0 * inv; res.x = fmaf(-m, m, q0 * inv);
            m = h1 * inv; res.y = fmaf(-m, m, q1 * inv);
            m = h2 * inv; res.z = fmaf(-m, m, q2 * inv);
            m = h3 * inv; res.w = fmaf(-m, m, q3 * inv);
            __builtin_nontemporal_store(
                res, reinterpret_cast<v4f*>(o + (size_t)(r0 + i - 4) * W + c0));
        }
        vc = vn;
        vn = vf;
    }
}

extern "C" void kernel_launch(void* const* d_in, const int* in_sizes, int n_in,
                              void* d_out, int out_size, void* d_ws, size_t ws_size,
                              hipStream_t stream) {
    const float* image = (const float*)d_in[0];
    float* out = (float*)d_out;

    const int H = 1024, W = 1024;
    const int BC = out_size / (H * W);   // 48

    dim3 grid(H / RH, BC);               // (32, 48) = 1536 blocks = 6/CU
    dim3 block(NT);
    lvar5x5_sep3_kernel<<<grid, block, 0, stream>>>(image, out, H, W);
}

// Round 7
// 338.761 us; speedup vs baseline: 1.0471x; 1.0471x over previous
//
#include <hip/hip_runtime.h>

// Local variance over a 5x5 sliding window, reflect padding.
// r2-style horizontal-first register stencil, but as a TIGHT ROLLED LOOP.
//
// DIAGNOSIS (r0/r2/r5): all previous kernels — register-tile, LDS-separable,
// any barrier/prefetch/occupancy variant — ran at ~0.4 instructions/cycle/CU
// (10x under front-end capability), VALUBusy 9-17%, HBM ~2.7 TB/s. Common
// factor: fully-unrolled straight-line bodies of 11-45 KB. With 12-24 waves
// per CU at different offsets of no-loop code, L1I (32 KiB) thrashes and
// every fetch comes from L2 (~200 cy). The fill kernel (tiny rolled loop)
// streams 6.5 TB/s at 9.6% occupancy on the same chip. Fix the code SHAPE,
// not the memory pipeline: hot loop ~4 KB, executed 12x per wave.
//
// Structure: per input row, 3 aligned float4 loads (cols c0-4..c0+7),
// horizontal sliding 5-sums of x and x^2; vertical 5-window via FIVE NAMED
// ring slots (A..E) rotated by a 5-row-unrolled loop body (all slot refs
// compile-time -> registers; #pragma unroll 1 keeps the outer loop rolled).
// Each thread: 4 cols x 64 output rows (68 input rows). Block = 256 threads
// spanning the full W=1024. Grid (H/64, B*C) = (16,48) = 768 blocks = 3/CU,
// all co-resident. 15 independent loads in flight per body iteration.
//
// Reflect (jnp "reflect"): rows via uniform clamp math. Columns (verified r2):
//   left  (tx==0):  col -2 -> col 2 auto (clamped v0); col -1 -> col 1 = v1.y
//   right (tx==255): col W -> col W-2 = v1.z; col W+1 -> col W-3 auto (clamped v2)

constexpr int NT = 256;
constexpr int RB = 64;   // output rows per block

struct Row8 { float h0, h1, h2, h3, q0, q1, q2, q3; };

__global__ __launch_bounds__(NT, 4)
void lvar5x5_rolled_kernel(const float* __restrict__ in, float* __restrict__ out,
                           int H, int W) {
    const int tx = threadIdx.x;              // 0..255, covers full row
    const int c0 = tx * 4;                   // this thread's 4 columns
    const int r0 = blockIdx.x * RB;          // first output row
    const size_t plane = (size_t)H * W;
    const float* __restrict__ img = in + (size_t)blockIdx.y * plane;
    float* __restrict__ o = out + (size_t)blockIdx.y * plane;

    const bool cL = (tx == 0);
    const bool cR = (tx == NT - 1);
    const int a0 = cL ? 0 : c0 - 4;          // clamped left halo load col
    const int a2 = cR ? c0 : c0 + 4;         // clamped right halo load col
    const float inv = 1.0f / 25.0f;

    Row8 A, B, C, D, E;                      // 5-row ring, named slots

    // Process input row ri (0..67; gy = r0-2+ri) -> horizontal 5-sums into s.
    auto ROW = [&](int ri, Row8& s) {
        int gy = r0 - 2 + ri;
        gy = (gy < 0) ? -gy : ((gy >= H) ? (2 * H - 2 - gy) : gy);
        const float* __restrict__ row = img + (size_t)gy * W;
        const float4 v0 = *reinterpret_cast<const float4*>(row + a0);
        const float4 v1 = *reinterpret_cast<const float4*>(row + c0);
        const float4 v2 = *reinterpret_cast<const float4*>(row + a2);

        const float x2 = v0.z;               // col c0-2 (auto at left edge)
        const float x3 = cL ? v1.y : v0.w;   // col c0-1 (reflect -1 -> 1)
        const float x4 = v1.x, x5 = v1.y, x6 = v1.z, x7 = v1.w;
        const float x8 = cR ? v1.z : v2.x;   // col c0+4 (reflect W -> W-2)
        const float x9 = v2.y;               // col c0+5 (auto at right edge)

        s.h0 = x2 + x3 + x4 + x5 + x6;
        s.h1 = s.h0 - x2 + x7;
        s.h2 = s.h1 - x3 + x8;
        s.h3 = s.h2 - x4 + x9;

        const float y2 = x2 * x2, y3 = x3 * x3, y4 = x4 * x4, y5 = x5 * x5;
        const float y6 = x6 * x6, y7 = x7 * x7, y8 = x8 * x8, y9 = x9 * x9;
        s.q0 = y2 + y3 + y4 + y5 + y6;
        s.q1 = s.q0 - y2 + y7;
        s.q2 = s.q1 - y3 + y8;
        s.q3 = s.q2 - y4 + y9;
    };

    // Emit output row r0+j from 5 ring slots (order irrelevant: pure sum).
    auto EMIT = [&](int j, const Row8& a, const Row8& b, const Row8& c,
                    const Row8& d, const Row8& e) {
        float4 res;
        float hs, qs, m;
        hs = a.h0 + b.h0 + c.h0 + d.h0 + e.h0;
        qs = a.q0 + b.q0 + c.q0 + d.q0 + e.q0;
        m = hs * inv; res.x = fmaf(-m, m, qs * inv);
        hs = a.h1 + b.h1 + c.h1 + d.h1 + e.h1;
        qs = a.q1 + b.q1 + c.q1 + d.q1 + e.q1;
        m = hs * inv; res.y = fmaf(-m, m, qs * inv);
        hs = a.h2 + b.h2 + c.h2 + d.h2 + e.h2;
        qs = a.q2 + b.q2 + c.q2 + d.q2 + e.q2;
        m = hs * inv; res.z = fmaf(-m, m, qs * inv);
        hs = a.h3 + b.h3 + c.h3 + d.h3 + e.h3;
        qs = a.q3 + b.q3 + c.q3 + d.q3 + e.q3;
        m = hs * inv; res.w = fmaf(-m, m, qs * inv);
        *reinterpret_cast<float4*>(o + (size_t)(r0 + j) * W + c0) = res;
    };

    // Prologue: input rows 0..3 -> slots A..D.
    ROW(0, A); ROW(1, B); ROW(2, C); ROW(3, D);

    // Main loop: 12 iterations x 5 output rows (outputs 0..59).
    // At iteration start: A=ri j, B=j+1, C=j+2, D=j+3.
#pragma unroll 1
    for (int j = 0; j < RB - 4; j += 5) {
        ROW(j + 4, E); EMIT(j + 0, A, B, C, D, E);
        ROW(j + 5, A); EMIT(j + 1, B, C, D, E, A);
        ROW(j + 6, B); EMIT(j + 2, C, D, E, A, B);
        ROW(j + 7, C); EMIT(j + 3, D, E, A, B, C);
        ROW(j + 8, D); EMIT(j + 4, E, A, B, C, D);
    }

    // Tail: outputs 60..63 (input rows 64..67).
    // After the loop: E=ri59, A=60, B=61, C=62, D=63.
    ROW(64, E); EMIT(60, A, B, C, D, E);
    ROW(65, A); EMIT(61, B, C, D, E, A);
    ROW(66, B); EMIT(62, C, D, E, A, B);
    ROW(67, C); EMIT(63, D, E, A, B, C);
}

extern "C" void kernel_launch(void* const* d_in, const int* in_sizes, int n_in,
                              void* d_out, int out_size, void* d_ws, size_t ws_size,
                              hipStream_t stream) {
    const float* image = (const float*)d_in[0];
    float* out = (float*)d_out;

    const int H = 1024, W = 1024;
    const int BC = out_size / (H * W);       // 48

    dim3 grid(H / RB, BC);                   // (16, 48) = 768 blocks = 3/CU
    dim3 block(NT);
    lvar5x5_rolled_kernel<<<grid, block, 0, stream>>>(image, out, H, W);
}